// Round 2
// baseline (437.517 us; speedup 1.0000x reference)
//
#include <hip/hip_runtime.h>

#define NGS 10

__global__ __launch_bounds__(256) void mapping_kernel(
    const float* __restrict__ var,          // (B, 40)
    const float* __restrict__ rel,          // (6, 10)
    const float* __restrict__ tick,         // (10,)
    const float* __restrict__ start,        // (2,)
    const float* __restrict__ lenmul,       // (1,)
    const unsigned char* __restrict__ nfse_p, // (1,) bool
    const float* __restrict__ maxt,         // (1,)
    float* __restrict__ out,                // (B, 10, 6)
    int B)
{
#pragma clang fp contract(off)
    int b = blockIdx.x * blockDim.x + threadIdx.x;
    if (b >= B) return;

    // ---- load this row's 40 floats (10x float4, row is 16B-aligned) ----
    float vv[40];
    const float4* vp = reinterpret_cast<const float4*>(var + (size_t)b * 40);
#pragma unroll
    for (int i = 0; i < 10; ++i) {
        float4 t = vp[i];
        vv[4 * i + 0] = t.x;
        vv[4 * i + 1] = t.y;
        vv[4 * i + 2] = t.z;
        vv[4 * i + 3] = t.w;
    }

    // ---- normalize: pair j of v[0..20) with v[20..40) ----
    float c[20], sn[20];
#pragma unroll
    for (int j = 0; j < 20; ++j) {
        float a = vv[j];
        float bb = vv[20 + j];
        float n = sqrtf(a * a + bb * bb);   // IEEE sqrt + IEEE div (no fast-math)
        c[j] = a / n;
        sn[j] = bb / n;
    }

    const float lm = lenmul[0];
    const float mt = maxt[0];
    const bool nfse = (nfse_p[0] != 0);

    float px = start[0];
    float py = start[1];

    float* orow = out + (size_t)b * (NGS * 6);

#pragma unroll
    for (int s = 0; s < NGS; ++s) {
        // wave-uniform per-step scalars (rel is row-major (6,10))
        const bool  is_sl = rel[0 * NGS + s] > 0.5f;
        const float sln   = rel[1 * NGS + s];
        const float scos  = rel[3 * NGS + s];
        const float ssin  = rel[4 * NGS + s];
        const float nd    = rel[5 * NGS + s];

        const float l  = lm * nd;
        // double-folded constants (match numpy's float32 promotion exactly)
        const float wl = 25.6f  + l * 0.5f;   // 0.05*512 + l*0.5
        const float wr = 486.4f - l * 0.5f;   // 0.95*512 - l*0.5
        const float wt = 19.2f  + l * 0.5f;   // 0.05*384 + l*0.5
        const float wb = 364.8f - l * 0.5f;   // 0.95*384 - l*0.5

        const float nr = (tick[s] <= mt) ? 1.0f : 0.0f;  // use_ds
        const float rr = 1.0f - nr;                      // rerand

        const float cos1 = c[s],      sin1 = sn[s];
        const float cos2 = c[NGS + s], sin2 = sn[NGS + s];

        const float rerand_x = 256.0f + 256.0f * vv[s];
        const float rerand_y = 192.0f + 192.0f * vv[20 + s];

        const float dx  = l * cos1;
        const float dy  = l * sin1;
        const float adx = fabsf(dx);
        const float ady = fabsf(dy);

        const float wvl  = (px < wl) ? 1.0f : 0.0f;
        const float wvr  = (px > wr) ? 1.0f : 0.0f;
        const float wvxm = ((px > wl) ? 1.0f : 0.0f) * ((px < wr) ? 1.0f : 0.0f);
        const float wvt  = (py < wt) ? 1.0f : 0.0f;
        const float wvb  = (py > wb) ? 1.0f : 0.0f;
        const float wvym = ((py > wt) ? 1.0f : 0.0f) * ((py < wb) ? 1.0f : 0.0f);

        const float x_delta = adx * wvl - adx * wvr + dx * wvxm;
        const float y_delta = ady * wvt - ady * wvb + dy * wvym;

        // keep the blend as mul+add (matches reference arithmetic & NaN flow)
        const float x = rr * rerand_x + nr * (px + x_delta);
        const float y = rr * rerand_y + nr * (py + y_delta);

        const float oa = cos2 * scos - sin2 * ssin;
        const float ob = cos2 * ssin + sin2 * scos;

        const float x_end = x + cos2 * sln;
        const float y_end = y + sin2 * sln;

        const float a2 = rr * cos2 + nr * cos1;
        const float b2 = rr * sin2 + nr * sin1;

        const float xn = x / 512.0f;   // X_MAX (exact: power of 2)
        const float yn = y / 384.0f;   // Y_MAX (IEEE div, matches np)

        const float o0 = xn;
        const float o1 = yn;
        const float o2 = is_sl ? oa : a2;
        const float o3 = is_sl ? ob : b2;
        const float o4 = is_sl ? (x_end / 512.0f) : xn;
        const float o5 = is_sl ? (y_end / 384.0f) : yn;

        // 3x float2 stores; (b*60 + s*6)*4 bytes is 8B-aligned
        float2* op = reinterpret_cast<float2*>(orow + s * 6);
        op[0] = make_float2(o0, o1);
        op[1] = make_float2(o2, o3);
        op[2] = make_float2(o4, o5);

        // carry update
        const float px_sl = nfse ? x_end : x;
        const float py_sl = nfse ? y_end : y;
        px = is_sl ? px_sl : x;
        py = is_sl ? py_sl : y;
    }
}

extern "C" void kernel_launch(void* const* d_in, const int* in_sizes, int n_in,
                              void* d_out, int out_size, void* d_ws, size_t ws_size,
                              hipStream_t stream) {
    const float* var    = (const float*)d_in[0];
    const float* rel    = (const float*)d_in[1];
    const float* tick   = (const float*)d_in[2];
    const float* start  = (const float*)d_in[3];
    const float* lenmul = (const float*)d_in[4];
    const unsigned char* nfse = (const unsigned char*)d_in[5];
    const float* maxt   = (const float*)d_in[6];
    float* out = (float*)d_out;

    const int B = in_sizes[0] / (4 * NGS);
    const int block = 256;
    const int grid = (B + block - 1) / block;
    mapping_kernel<<<grid, block, 0, stream>>>(var, rel, tick, start, lenmul,
                                               nfse, maxt, out, B);
}